// Round 4
// baseline (303.431 us; speedup 1.0000x reference)
//
#include <hip/hip_runtime.h>
#include <math.h>

#define B_N 2048
#define L_N 64
#define D_N 256   // EMBED_DIM
#define U_N 512   // UNITS
#define NB  8     // batches per attn block (grid = 256 = 1 block/CU)

typedef __attribute__((ext_vector_type(8))) short bf16x8;   // 8 bf16 = 4 VGPRs
typedef __attribute__((ext_vector_type(4))) float f32x4;    // MFMA 16x16 acc

// tanh(x) = 1 - 2/(2^(x*2*log2e)+1)
__device__ __forceinline__ float fast_tanh(float x) {
    float e = __builtin_amdgcn_exp2f(x * 2.8853900817779268f);
    float r = __builtin_amdgcn_rcpf(e + 1.0f);
    return fmaf(-2.0f, r, 1.0f);
}
// fp32 -> bf16 round-to-nearest-even
__device__ __forceinline__ ushort f2bf(float x) {
    uint b = __float_as_uint(x);
    uint r = (b + 0x7FFF + ((b >> 16) & 1)) >> 16;
    return (ushort)r;
}
__device__ __forceinline__ float bf2f(ushort u) {
    uint v = ((uint)u) << 16;
    return __uint_as_float(v);
}

// ---------------------------------------------------------------------------
// K0: pack W1 [256,512] and W2 [512,512] fp32 -> bf16 MFMA B-fragment order.
// chunk g = (ntg*KS + ks)*64 + lane holds W[ks*32 + (lane>>4)*8 + j][ntg*16 + (lane&15)]
// ---------------------------------------------------------------------------
__global__ __launch_bounds__(256) void pack_weights(
    const float* __restrict__ W1, const float* __restrict__ W2,
    ushort* __restrict__ W1p, ushort* __restrict__ W2p)
{
    ushort tmp[8];
    if (blockIdx.x < 64) {
        int g = blockIdx.x * 256 + threadIdx.x;      // 0..16383
        int ntg = g >> 9, ks = (g >> 6) & 7, lane = g & 63;
        int n  = ntg * 16 + (lane & 15);
        int kb = ks * 32 + (lane >> 4) * 8;
#pragma unroll
        for (int j = 0; j < 8; ++j) tmp[j] = f2bf(W1[(kb + j) * U_N + n]);
        *(uint4*)&W1p[(size_t)g * 8] = *(uint4*)tmp;
    } else {
        int g = (blockIdx.x - 64) * 256 + threadIdx.x;  // 0..32767
        int ntg = g >> 10, ks = (g >> 6) & 15, lane = g & 63;
        int n  = ntg * 16 + (lane & 15);
        int kb = ks * 32 + (lane >> 4) * 8;
#pragma unroll
        for (int j = 0; j < 8; ++j) tmp[j] = f2bf(W2[(kb + j) * U_N + n]);
        *(uint4*)&W2p[(size_t)g * 8] = *(uint4*)tmp;
    }
}

// ---------------------------------------------------------------------------
// K1: ph = hidden @ W2 + b1 + b2 via bf16 MFMA, stored bf16. (R0 version)
// ---------------------------------------------------------------------------
__global__ __launch_bounds__(256) void proj_h_mfma(
    const float* __restrict__ hidden, const ushort* __restrict__ W2p,
    const float* __restrict__ b1, const float* __restrict__ b2,
    ushort* __restrict__ ph)
{
    __shared__ ushort As[16 * 512];   // 16 KB

    const int t  = threadIdx.x;
    const int b0 = blockIdx.x * 16;
    const int u0 = blockIdx.y * 128;

#pragma unroll
    for (int i = 0; i < 4; ++i) {
        int f = t + i * 256;
        int m = f >> 6, c = f & 63;
        float4 x0 = *(const float4*)&hidden[(b0 + m) * U_N + c * 8];
        float4 x1 = *(const float4*)&hidden[(b0 + m) * U_N + c * 8 + 4];
        ushort tmp[8] = {f2bf(x0.x), f2bf(x0.y), f2bf(x0.z), f2bf(x0.w),
                         f2bf(x1.x), f2bf(x1.y), f2bf(x1.z), f2bf(x1.w)};
        *(uint4*)&As[(m * 64 + (c ^ (m & 7))) * 8] = *(uint4*)tmp;
    }
    __syncthreads();

    const int w = t >> 6, lane = t & 63;
    const int ml = lane & 15, q = lane >> 4;

    f32x4 acc[2];
#pragma unroll
    for (int nt = 0; nt < 2; ++nt) acc[nt] = (f32x4){0.f, 0.f, 0.f, 0.f};

    for (int ks = 0; ks < 16; ++ks) {
        int c = ks * 4 + q;
        bf16x8 a = *(const bf16x8*)&As[(ml * 64 + (c ^ (ml & 7))) * 8];
        bf16x8 bb[2];
#pragma unroll
        for (int nt = 0; nt < 2; ++nt) {
            int ntg = blockIdx.y * 8 + w * 2 + nt;
            bb[nt] = *(const bf16x8*)&W2p[(size_t)((ntg * 16 + ks) * 64 + lane) * 8];
        }
#pragma unroll
        for (int nt = 0; nt < 2; ++nt)
            acc[nt] = __builtin_amdgcn_mfma_f32_16x16x32_bf16(a, bb[nt], acc[nt], 0, 0, 0);
    }

#pragma unroll
    for (int nt = 0; nt < 2; ++nt) {
        int n = u0 + (w * 2 + nt) * 16 + ml;
        float bias = b1[n] + b2[n];
#pragma unroll
        for (int r = 0; r < 4; ++r)
            ph[(size_t)(b0 + q * 4 + r) * U_N + n] = f2bf(acc[nt][r] + bias);
    }
}

// ---------------------------------------------------------------------------
// K2: fused attention, 512 threads = 8 waves, wave owns a 64-u strip.
// acc[4][4] (64 VGPR) held once -> A-fragments read ONCE per iter (32
// ds_read_b128/wave vs 128 in the 4-wave/uc-loop version: the LDS pipe was
// the measured bottleneck at MfmaUtil 15% / VALUBusy 27%).
// Conversion is back in-kernel (no fbf pass): staging of b+1 is reg-staged
// fp32->bf16 in two halves with a NAMED 4xfloat4 payload (16 VGPR; R1's
// spill came from a 64-reg array payload, R3 proved ~148 natural regs OK):
//   ISSUE_H0 -> ks 0..3 -> WRITE_H0 + ISSUE_H1 -> ks 4..7 -> fold -> WRITE_H1
// HBM latency hides under the MFMA halves. LDS 68.3 KB -> 1 block/CU.
// ---------------------------------------------------------------------------
__global__ __launch_bounds__(512) void attn_kernel(
    const float* __restrict__ features, const ushort* __restrict__ W1p,
    const float* __restrict__ V, const float* __restrict__ bV,
    const ushort* __restrict__ ph, float* __restrict__ out)
{
    __shared__ ushort As[2][64 * 256];   // 2 x 32 KB, chunk (m,c) at m*32 + (c^(m&31))
    __shared__ float lpart[8][64];
    __shared__ float ctxp[2][256];
    __shared__ float wls[64];

    const int t    = threadIdx.x;        // 0..511
    const int w    = t >> 6;             // 0..7
    const int lane = t & 63;
    const int ml   = lane & 15;
    const int q    = lane >> 4;
    const int b0   = blockIdx.x * NB;

    float4 pa0, pa1, pb0, pb1;           // staging payload: 16 VGPRs, named

    // chunk ch = t + i*512 (i in 0..3); LDS pos (m*32+cc) holds logical chunk
    // (m, cc^(m&31)) so the swizzled a-frag read returns logical (m,c).
#define ISSUE_HALF(bb, i0) do {                                               \
        const float* fb_ = features + (size_t)(bb) * (L_N * D_N);             \
        { int ch_ = t + (i0) * 512; int m_ = ch_ >> 5, cc_ = ch_ & 31;        \
          const float* s_ = &fb_[m_ * D_N + (cc_ ^ (m_ & 31)) * 8];           \
          pa0 = *(const float4*)s_; pa1 = *(const float4*)(s_ + 4); }         \
        { int ch_ = t + (i0 + 1) * 512; int m_ = ch_ >> 5, cc_ = ch_ & 31;    \
          const float* s_ = &fb_[m_ * D_N + (cc_ ^ (m_ & 31)) * 8];           \
          pb0 = *(const float4*)s_; pb1 = *(const float4*)(s_ + 4); }         \
    } while (0)

#define WRITE_HALF(buf, i0) do {                                              \
        { int ch_ = t + (i0) * 512; int m_ = ch_ >> 5, cc_ = ch_ & 31;        \
          ushort tv_[8] = {f2bf(pa0.x), f2bf(pa0.y), f2bf(pa0.z), f2bf(pa0.w),\
                           f2bf(pa1.x), f2bf(pa1.y), f2bf(pa1.z), f2bf(pa1.w)};\
          *(uint4*)&As[buf][((m_ * 32 + cc_)) * 8] = *(uint4*)tv_; }          \
        { int ch_ = t + (i0 + 1) * 512; int m_ = ch_ >> 5, cc_ = ch_ & 31;    \
          ushort tv_[8] = {f2bf(pb0.x), f2bf(pb0.y), f2bf(pb0.z), f2bf(pb0.w),\
                           f2bf(pb1.x), f2bf(pb1.y), f2bf(pb1.z), f2bf(pb1.w)};\
          *(uint4*)&As[buf][((m_ * 32 + cc_)) * 8] = *(uint4*)tv_; }          \
    } while (0)

#define KSTEP(ks) do {                                                        \
        if ((ks) < 7) {                                                       \
            _Pragma("unroll")                                                 \
            for (int nt = 0; nt < 4; ++nt)                                    \
                bfn[nt] = *(const bf16x8*)&W1w[(size_t)((nt * 8 + (ks) + 1) * 64 + lane) * 8]; \
        }                                                                     \
        bf16x8 a_[4];                                                         \
        _Pragma("unroll")                                                     \
        for (int mt = 0; mt < 4; ++mt) {                                      \
            int m_ = mt * 16 + ml, c_ = (ks) * 4 + q;                         \
            a_[mt] = *(const bf16x8*)&As[cur][(m_ * 32 + (c_ ^ (m_ & 31))) * 8]; \
        }                                                                     \
        _Pragma("unroll")                                                     \
        for (int nt = 0; nt < 4; ++nt)                                        \
            _Pragma("unroll")                                                 \
            for (int mt = 0; mt < 4; ++mt)                                    \
                acc[mt][nt] = __builtin_amdgcn_mfma_f32_16x16x32_bf16(        \
                    a_[mt], bfc[nt], acc[mt][nt], 0, 0, 0);                   \
        if ((ks) < 7) {                                                       \
            _Pragma("unroll")                                                 \
            for (int nt = 0; nt < 4; ++nt) bfc[nt] = bfn[nt];                 \
        }                                                                     \
    } while (0)

    // prologue: stage b0 into buffer 0 (both halves)
    ISSUE_HALF(b0, 0);
    WRITE_HALF(0, 0);
    ISSUE_HALF(b0, 2);
    WRITE_HALF(0, 2);
    __syncthreads();

    const ushort* W1w = W1p + (size_t)(w * 4) * 8 * 64 * 8;  // wave's 64-u strip (4 ntg)
    int cur = 0;

    for (int bi = 0; bi < NB; ++bi) {
        const int b = b0 + bi;
        const bool pre = (bi + 1 < NB);

        // T14 issue-early: first half of b+1's tile, drains under ks 0..3
        if (pre) ISSUE_HALF(b + 1, 0);
        __builtin_amdgcn_sched_barrier(0);

        f32x4 acc[4][4];
#pragma unroll
        for (int mt = 0; mt < 4; ++mt)
#pragma unroll
            for (int nt = 0; nt < 4; ++nt)
                acc[mt][nt] = (f32x4){0.f, 0.f, 0.f, 0.f};

        bf16x8 bfc[4], bfn[4];
#pragma unroll
        for (int nt = 0; nt < 4; ++nt)
            bfc[nt] = *(const bf16x8*)&W1w[(size_t)((nt * 8) * 64 + lane) * 8];

        KSTEP(0); KSTEP(1); KSTEP(2); KSTEP(3);

        // write-late half 0 (loads landed under ks 0..3); issue half 1
        if (pre) {
            WRITE_HALF(cur ^ 1, 0);
            ISSUE_HALF(b + 1, 2);
        }
        __builtin_amdgcn_sched_barrier(0);

        KSTEP(4); KSTEP(5); KSTEP(6); KSTEP(7);

        // fold into persistent lp. D layout: n = nt*16+ml (col), m = mt*16+q*4+r
        float lp[16];
#pragma unroll
        for (int j = 0; j < 16; ++j) lp[j] = 0.f;
#pragma unroll
        for (int nt = 0; nt < 4; ++nt) {
            int n = w * 64 + nt * 16 + ml;
            float phv = bf2f(ph[(size_t)b * U_N + n]);
            float vv  = V[n];
#pragma unroll
            for (int mt = 0; mt < 4; ++mt)
#pragma unroll
                for (int r = 0; r < 4; ++r) {
                    float s = fast_tanh(acc[mt][nt][r] + phv);
                    lp[mt * 4 + r] = fmaf(s, vv, lp[mt * 4 + r]);
                }
        }

        // reduce over the 16 n-lanes (xor 1,2,4,8 stays within q-group)
#pragma unroll
        for (int off = 1; off <= 8; off <<= 1)
#pragma unroll
            for (int j = 0; j < 16; ++j)
                lp[j] += __shfl_xor(lp[j], off);

        // write-late half 1 (loads landed under ks 4..7 + fold)
        if (pre) WRITE_HALF(cur ^ 1, 2);

        if (ml == 0) {
#pragma unroll
            for (int mt = 0; mt < 4; ++mt)
#pragma unroll
                for (int r = 0; r < 4; ++r)
                    lpart[w][mt * 16 + q * 4 + r] = lp[mt * 4 + r];
        }
        __syncthreads();   // BARRIER B: lpart ready (also covers WRITE_H0/H1)

        if (t < 64) {
            float lsum = bV[0];
#pragma unroll
            for (int ww = 0; ww < 8; ++ww) lsum += lpart[ww][t];
            float mx = lsum;
#pragma unroll
            for (int off = 32; off > 0; off >>= 1)
                mx = fmaxf(mx, __shfl_xor(mx, off));
            float e = __expf(lsum - mx);
            float ssum = e;
#pragma unroll
            for (int off = 32; off > 0; off >>= 1)
                ssum += __shfl_xor(ssum, off);
            float wt = e / ssum;
            wls[t] = wt;
            out[(size_t)B_N * D_N + (size_t)b * L_N + t] = wt;
        }
        __syncthreads();   // BARRIER C: wls ready

        // context partials: thread t -> d = t&255, l-half h = t>>8
        {
            int d = t & 255, h = t >> 8;
            float cx = 0.f;
#pragma unroll 8
            for (int li = 0; li < 32; ++li) {
                int l = h * 32 + li;
                ushort u = As[cur][(l * 32 + ((d >> 3) ^ (l & 31))) * 8 + (d & 7)];
                cx = fmaf(wls[l], bf2f(u), cx);
            }
            ctxp[h][d] = cx;
        }
        __syncthreads();   // BARRIER D: ctxp ready; As[cur] free; As[cur^1] staged

        if (t < 256) out[(size_t)b * D_N + t] = ctxp[0][t] + ctxp[1][t];

        cur ^= 1;
    }
#undef ISSUE_HALF
#undef WRITE_HALF
#undef KSTEP
}

// ---------------------------------------------------------------------------
extern "C" void kernel_launch(void* const* d_in, const int* in_sizes, int n_in,
                              void* d_out, int out_size, void* d_ws, size_t ws_size,
                              hipStream_t stream) {
    const float* features = (const float*)d_in[0];
    const float* hidden   = (const float*)d_in[1];
    const float* W1       = (const float*)d_in[2];
    const float* b1       = (const float*)d_in[3];
    const float* W2       = (const float*)d_in[4];
    const float* b2       = (const float*)d_in[5];
    const float* V        = (const float*)d_in[6];
    const float* bV       = (const float*)d_in[7];
    float* out = (float*)d_out;

    // ws: ph bf16 2 MB | W1p 256 KB | W2p 512 KB
    ushort* ph  = (ushort*)d_ws;
    ushort* W1p = (ushort*)((char*)d_ws + (size_t)B_N * U_N * 2);
    ushort* W2p = (ushort*)((char*)d_ws + (size_t)B_N * U_N * 2 + (size_t)D_N * U_N * 2);

    pack_weights<<<192, 256, 0, stream>>>(W1, W2, W1p, W2p);
    proj_h_mfma<<<dim3(B_N / 16, U_N / 128), 256, 0, stream>>>(hidden, W2p, b1, b2, ph);
    attn_kernel<<<B_N / NB, 512, 0, stream>>>(features, W1p, V, bV, ph, out);
}